// Round 2
// baseline (97269.507 us; speedup 1.0000x reference)
//
#include <hip/hip_runtime.h>
#include <cstdint>
#include <math.h>

typedef unsigned int u32;
typedef unsigned long long u64;

// JAX threefry scheme: partitionable (validated round 1: error 964 -> 24).
#define TF_PARTITIONABLE 1

#define NU 6144
#define NB 32
#define NTOT (NU * NB)      // 196608
#define NWORD 96            // u64 words per sample row
#define NCH 16              // i-chunks per GEMM (f64 partials, same bytes as 32 f32)
#define CHI 384             // i per chunk (NCH*CHI = NU)
#define HALF_BIG 98304u
#define HALF_SMALL 16u

struct Key { u32 a, b; };
struct UVec { float u[NB]; };

// ---------------- threefry2x32 (20 rounds), matches jax._src.prng ----------------
__host__ __device__ __forceinline__ void tf2x32(u32 k0, u32 k1, u32 x0, u32 x1, u32& o0, u32& o1) {
  const u32 k2 = k0 ^ k1 ^ 0x1BD11BDAu;
#define TFR(r) { x0 += x1; x1 = (x1 << r) | (x1 >> (32 - r)); x1 ^= x0; }
  x0 += k0; x1 += k1;
  TFR(13) TFR(15) TFR(26) TFR(6)  x0 += k1; x1 += k2 + 1u;
  TFR(17) TFR(29) TFR(16) TFR(24) x0 += k2; x1 += k0 + 2u;
  TFR(13) TFR(15) TFR(26) TFR(6)  x0 += k0; x1 += k1 + 3u;
  TFR(17) TFR(29) TFR(16) TFR(24) x0 += k1; x1 += k2 + 4u;
  TFR(13) TFR(15) TFR(26) TFR(6)  x0 += k2; x1 += k0 + 5u;
#undef TFR
  o0 = x0; o1 = x1;
}

__host__ __device__ __forceinline__ u32 rbits(u32 k0, u32 k1, u32 t, u32 half) {
#if TF_PARTITIONABLE
  (void)half;
  u32 a, b; tf2x32(k0, k1, 0u, t, a, b); return a ^ b;
#else
  u32 a, b;
  if (t < half) { tf2x32(k0, k1, t, half + t, a, b); return a; }
  tf2x32(k0, k1, t - half, t, a, b); return b;
#endif
}

__host__ __device__ __forceinline__ float u01f(u32 bits) {
  union { u32 u; float f; } c; c.u = (bits >> 9) | 0x3f800000u;
  return c.f - 1.0f;
}

// ---------------- device kernels ----------------

__global__ __launch_bounds__(256) void k_pos_v(const float* __restrict__ vin,
                                               float* __restrict__ xf, u64* __restrict__ pk) {
  int tid = blockIdx.x * 256 + threadIdx.x;          // 24576 = 32*768
  int b = tid / 768, p = tid % 768;
  float x = vin[tid];
  int q = (int)floorf(x * 256.0f);
  q = q < 0 ? 0 : (q > 255 ? 255 : q);
  ((unsigned char*)pk)[b * 768 + p] = (unsigned char)q;   // byte == 8 LSB-first bits
  int ubase = p * 8;
#pragma unroll
  for (int bit = 0; bit < 8; ++bit)
    xf[(size_t)(ubase + bit) * NB + b] = (float)((q >> bit) & 1);
}

__global__ __launch_bounds__(256) void k_bern(u32 k0, u32 k1,
                                              float* __restrict__ xf, u64* __restrict__ pk) {
  int tid = blockIdx.x * 256 + threadIdx.x;          // 196608
  int b = tid / NU, j = tid % NU;
  float u = u01f(rbits(k0, k1, (u32)tid, HALF_BIG));
  bool s = u < 0.5f;
  u64 m = __ballot(s);
  if ((threadIdx.x & 63) == 0) pk[tid >> 6] = m;
  xf[(size_t)j * NB + b] = s ? 1.0f : 0.0f;
}

// sample (optionally merged over even mask): state = samp(even[b] ? fE : fO)
// T=1 decision evaluated in double (true-value decision; ref noise is the only flip source).
__global__ __launch_bounds__(256) void k_samp(const float* __restrict__ fE, const float* __restrict__ fO,
                                              u32 even, int t1, u32 k0, u32 k1,
                                              float* __restrict__ xf, u64* __restrict__ pk) {
  int tid = blockIdx.x * 256 + threadIdx.x;
  int b = tid / NU, j = tid % NU;
  float f = ((even >> b) & 1u) ? fE[tid] : fO[tid];
  bool s;
  if (t1) {
    double u = (double)u01f(rbits(k0, k1, (u32)tid, HALF_BIG));
    double sg = 1.0 / (1.0 + exp(-(double)f));
    s = u < sg;
  } else s = (f >= 0.0f);
  u64 m = __ballot(s);
  if ((threadIdx.x & 63) == 0) pk[tid >> 6] = m;
  xf[(size_t)j * NB + b] = s ? 1.0f : 0.0f;
}

#define DFMA32 \
  acc[ 0]=fma((double)x0.x,w,acc[ 0]); acc[ 1]=fma((double)x0.y,w,acc[ 1]); acc[ 2]=fma((double)x0.z,w,acc[ 2]); acc[ 3]=fma((double)x0.w,w,acc[ 3]); \
  acc[ 4]=fma((double)x1.x,w,acc[ 4]); acc[ 5]=fma((double)x1.y,w,acc[ 5]); acc[ 6]=fma((double)x1.z,w,acc[ 6]); acc[ 7]=fma((double)x1.w,w,acc[ 7]); \
  acc[ 8]=fma((double)x2.x,w,acc[ 8]); acc[ 9]=fma((double)x2.y,w,acc[ 9]); acc[10]=fma((double)x2.z,w,acc[10]); acc[11]=fma((double)x2.w,w,acc[11]); \
  acc[12]=fma((double)x3.x,w,acc[12]); acc[13]=fma((double)x3.y,w,acc[13]); acc[14]=fma((double)x3.z,w,acc[14]); acc[15]=fma((double)x3.w,w,acc[15]); \
  acc[16]=fma((double)x4.x,w,acc[16]); acc[17]=fma((double)x4.y,w,acc[17]); acc[18]=fma((double)x4.z,w,acc[18]); acc[19]=fma((double)x4.w,w,acc[19]); \
  acc[20]=fma((double)x5.x,w,acc[20]); acc[21]=fma((double)x5.y,w,acc[21]); acc[22]=fma((double)x5.z,w,acc[22]); acc[23]=fma((double)x5.w,w,acc[23]); \
  acc[24]=fma((double)x6.x,w,acc[24]); acc[25]=fma((double)x6.y,w,acc[25]); acc[26]=fma((double)x6.z,w,acc[26]); acc[27]=fma((double)x6.w,w,acc[27]); \
  acc[28]=fma((double)x7.x,w,acc[28]); acc[29]=fma((double)x7.y,w,acc[29]); acc[30]=fma((double)x7.z,w,acc[30]); acc[31]=fma((double)x7.w,w,acc[31]);

// out[b][j] = sum_i x[i][b] * W[i][j]   (x @ W), f64 chunk partials (exact)
__global__ __launch_bounds__(64) void k_gemm_n(const float* __restrict__ W, const float* __restrict__ xf,
                                               double* __restrict__ part) {
  int wg = blockIdx.x;                 // 1536 = 96 jtiles * 16 chunks (jt fastest)
  int jt = wg % 96, c = wg / 96;
  int lane = threadIdx.x;
  int j = jt * 64 + lane;
  const float* wp = W + (size_t)c * CHI * NU + j;
  const float* xp = xf + (size_t)c * CHI * NB;
  double acc[32];
#pragma unroll
  for (int b = 0; b < 32; ++b) acc[b] = 0.0;
  for (int i = 0; i < CHI; ++i) {
    double w = (double)wp[(size_t)i * NU];
    const float4* xq = (const float4*)(xp + i * NB);
    float4 x0 = xq[0], x1 = xq[1], x2 = xq[2], x3 = xq[3];
    float4 x4 = xq[4], x5 = xq[5], x6 = xq[6], x7 = xq[7];
    DFMA32
  }
  double* pp = part + (size_t)c * NTOT + j;
#pragma unroll
  for (int b = 0; b < 32; ++b) pp[(size_t)b * NU] = acc[b];
}

// out[b][j] = sum_i x[i][b] * W[j][i]   (x @ W.T) via LDS-transposed W tiles, f64 acc
__global__ __launch_bounds__(64) void k_gemm_t(const float* __restrict__ W, const float* __restrict__ xf,
                                               double* __restrict__ part) {
  __shared__ float lw[32 * 73];        // [i_local][j_local] padded stride 73
  int wg = blockIdx.x;
  int jt = wg % 96, c = wg / 96;
  int tid = threadIdx.x;
  int jbase = jt * 64;
  int q = tid & 7, a = tid >> 3;
  double acc[32];
#pragma unroll
  for (int b = 0; b < 32; ++b) acc[b] = 0.0;
  for (int s = 0; s < CHI / 32; ++s) {
    int ib = c * CHI + s * 32;
#pragma unroll
    for (int r = 0; r < 8; ++r) {
      int j = jbase + r * 8 + a;
      float4 w4 = *(const float4*)(W + (size_t)j * NU + ib + q * 4);
      lw[(q * 4 + 0) * 73 + r * 8 + a] = w4.x;
      lw[(q * 4 + 1) * 73 + r * 8 + a] = w4.y;
      lw[(q * 4 + 2) * 73 + r * 8 + a] = w4.z;
      lw[(q * 4 + 3) * 73 + r * 8 + a] = w4.w;
    }
    __syncthreads();
    for (int ii = 0; ii < 32; ++ii) {
      double w = (double)lw[ii * 73 + tid];
      const float4* xq = (const float4*)(xf + (size_t)(ib + ii) * NB);
      float4 x0 = xq[0], x1 = xq[1], x2 = xq[2], x3 = xq[3];
      float4 x4 = xq[4], x5 = xq[5], x6 = xq[6], x7 = xq[7];
      DFMA32
    }
    __syncthreads();
  }
  double* pp = part + (size_t)c * NTOT + jbase + tid;
#pragma unroll
  for (int b = 0; b < 32; ++b) pp[(size_t)b * NU] = acc[b];
}

// field[b][j] = (src? src : 0) + (bias? bias[j] : 0) + sum_c part[c][b][j]  (f64, exact)
__global__ __launch_bounds__(256) void k_reduce(const double* __restrict__ part, const float* __restrict__ bias,
                                                const float* __restrict__ src, float* __restrict__ out) {
  int tid = blockIdx.x * 256 + threadIdx.x;
  int j = tid % NU;
  double s = src ? (double)src[tid] : 0.0;
  if (bias) s += (double)bias[j];
#pragma unroll 4
  for (int c = 0; c < NCH; ++c) s += part[(size_t)c * NTOT + tid];
  out[tid] = (float)s;
}

// e[b] = -( sum_j v_j*b0_j + sum_j h0_j*f1[b][j] + sum_j h1_j*f2[b][j] ), f64 accumulation
__global__ __launch_bounds__(256) void k_energy(const u64* __restrict__ pkv, const u64* __restrict__ pkh0,
                                                const u64* __restrict__ pkh1, const float* __restrict__ f1,
                                                const float* __restrict__ f2, const float* __restrict__ b0,
                                                float* __restrict__ eout) {
  __shared__ double red[256];
  int b = blockIdx.x, t = threadIdx.x;
  double s = 0.0;
  for (int j = t; j < NU; j += 256) {
    int w = j >> 6, bit = j & 63;
    if ((pkv [b * NWORD + w] >> bit) & 1ull) s += (double)b0[j];
    if ((pkh0[b * NWORD + w] >> bit) & 1ull) s += (double)f1[(size_t)b * NU + j];
    if ((pkh1[b * NWORD + w] >> bit) & 1ull) s += (double)f2[(size_t)b * NU + j];
  }
  red[t] = s; __syncthreads();
  for (int off = 128; off > 0; off >>= 1) { if (t < off) red[t] += red[t + off]; __syncthreads(); }
  if (t == 0) eout[b] = (float)(-red[0]);
}

// MH accept + coupling bookkeeping (one wave per sample); accept math in double
__global__ __launch_bounds__(64) void k_accept(float* __restrict__ ecur, const float* __restrict__ eprop,
                                               float* __restrict__ erun, u32* __restrict__ conv,
                                               u32* __restrict__ accf,
                                               const u64* __restrict__ pv, const u64* __restrict__ pcv,
                                               const u64* __restrict__ ph0, const u64* __restrict__ pch0,
                                               const u64* __restrict__ ph1, const u64* __restrict__ pch1,
                                               UVec uv, int first) {
  int b = blockIdx.x, t = threadIdx.x;
  u64 diff = 0ull;
  for (int w = t; w < NWORD; w += 64) {
    size_t o = (size_t)b * NWORD + w;
    if (pv) diff |= pv[o] ^ pcv[o];
    diff |= ph0[o] ^ pch0[o];
    diff |= ph1[o] ^ pch1[o];
  }
  int neq = __any(diff != 0ull);
  if (t == 0) {
    float ec = ecur[b], ep = eprop[b];
    bool acc = (double)uv.u[b] < exp(fmin((double)ec - (double)ep, 0.0));
    bool m = first ? true : (conv[b] == 0u);
    bool upd = m && acc;
    if (first) erun[b] = acc ? ep : ec;
    else if (upd) erun[b] += (ep - ec);
    if (upd) ecur[b] = ep;
    u32 c2 = acc ? (neq ? 0u : 1u) : 1u;
    conv[b] = first ? c2 : (conv[b] | c2);
    accf[b] = upd ? 1u : 0u;
  }
}

__global__ __launch_bounds__(256) void k_merge_xf(const u32* __restrict__ accf,
                                                  const float* __restrict__ pa, float* __restrict__ ca,
                                                  const float* __restrict__ pb, float* __restrict__ cb,
                                                  const float* __restrict__ pc, float* __restrict__ cc) {
  int tid = blockIdx.x * 256 + threadIdx.x;
  int b = tid & 31;                       // xf layout [unit][b]
  if (accf[b]) {
    ca[tid] = pa[tid];
    cb[tid] = pb[tid];
    if (pc) cc[tid] = pc[tid];
  }
}

__global__ __launch_bounds__(256) void k_merge_pk(const u32* __restrict__ accf,
                                                  const u64* __restrict__ pa, u64* __restrict__ ca,
                                                  const u64* __restrict__ pb, u64* __restrict__ cb,
                                                  const u64* __restrict__ pc, u64* __restrict__ cc) {
  int w = blockIdx.x * 256 + threadIdx.x;
  if (w >= NB * NWORD) return;
  int b = w / NWORD;
  if (accf[b]) {
    ca[w] = pa[w];
    cb[w] = pb[w];
    if (pc) cc[w] = pc[w];
  }
}

__global__ void k_final(const float* __restrict__ ep, const float* __restrict__ en, float* __restrict__ out) {
  int b = threadIdx.x;
  if (b < NB) out[b] = ep[b] - en[b];
}

// ---------------- host-side key derivation ----------------
static void split_keys(Key k, int n, Key* out) {
#if TF_PARTITIONABLE
  for (int i = 0; i < n; ++i) { u32 a, b; tf2x32(k.a, k.b, 0u, (u32)i, a, b); out[i].a = a; out[i].b = b; }
#else
  u32 flat[64];
  for (int i = 0; i < n; ++i) { u32 a, b; tf2x32(k.a, k.b, (u32)i, (u32)(n + i), a, b); flat[i] = a; flat[n + i] = b; }
  for (int i = 0; i < n; ++i) { out[i].a = flat[2 * i]; out[i].b = flat[2 * i + 1]; }
#endif
}
static u32 mask32(Key k) {
  u32 m = 0;
  for (int b = 0; b < NB; ++b)
    if (u01f(rbits(k.a, k.b, (u32)b, HALF_SMALL)) < 0.5f) m |= (1u << b);
  return m;
}

extern "C" void kernel_launch(void* const* d_in, const int* in_sizes, int n_in,
                              void* d_out, int out_size, void* d_ws, size_t ws_size,
                              hipStream_t stream) {
  const float* vin = (const float*)d_in[0];
  const float* W0  = (const float*)d_in[1];
  const float* W1  = (const float*)d_in[2];
  const float* b0  = (const float*)d_in[3];
  const float* b1  = (const float*)d_in[4];
  const float* b2  = (const float*)d_in[5];
  float* outp = (float*)d_out;

  // ---- workspace layout ----
  char* ws = (char*)d_ws;
  size_t off = 0;
  auto alloc = [&](size_t bytes) -> void* {
    void* p = ws + off; off += (bytes + 255) & ~(size_t)255; return p;
  };
  enum { SV = 0, SH0, SH1, SVE, SH1E, SH0O, SVP, SH0P, SH1P, NS };
  enum { IV = 0, IA, IB, IC, ID, IE, IF2, IP1, IP2, IC2, NF };
  float* XF[NS]; u64* PK[NS]; float* F[NF];
  for (int s = 0; s < NS; ++s) XF[s] = (float*)alloc((size_t)NTOT * 4);
  for (int f = 0; f < NF; ++f) F[f]  = (float*)alloc((size_t)NTOT * 4);
  double* PART = (double*)alloc((size_t)NCH * NTOT * 8);
  for (int s = 0; s < NS; ++s) PK[s] = (u64*)alloc((size_t)NB * NWORD * 8);
  float* E_CUR  = (float*)alloc(256);
  float* E_PROP = (float*)alloc(256);
  float* E_POS  = (float*)alloc(256);
  float* E_NEG  = (float*)alloc(256);
  u32*   ACC    = (u32*)alloc(256);
  u32*   CONV   = (u32*)alloc(256);
  if (off > ws_size) return;  // insufficient workspace

  // ---- host RNG: full key tree from jax.random.key(42) ----
  Key root{0u, 42u};
  Key ks[13]; split_keys(root, 13, ks);
  const Key KZ{0u, 0u};

  // ---- launch helpers ----
  auto GT = [&](const float* Wm, int xs, const float* bias, const float* src, float* dst) {
    k_gemm_t<<<dim3(96 * NCH), dim3(64), 0, stream>>>(Wm, XF[xs], PART);
    k_reduce<<<dim3(768), dim3(256), 0, stream>>>(PART, bias, src, dst);
  };
  auto GN = [&](const float* Wm, int xs, const float* bias, const float* src, float* dst) {
    k_gemm_n<<<dim3(96 * NCH), dim3(64), 0, stream>>>(Wm, XF[xs], PART);
    k_reduce<<<dim3(768), dim3(256), 0, stream>>>(PART, bias, src, dst);
  };
  auto SAMP = [&](const float* fE, const float* fO, u32 even, int t1, Key k, int dst) {
    k_samp<<<dim3(768), dim3(256), 0, stream>>>(fE, fO, even, t1, k.a, k.b, XF[dst], PK[dst]);
  };
  auto BERN = [&](Key k, int dst) {
    k_bern<<<dim3(768), dim3(256), 0, stream>>>(k.a, k.b, XF[dst], PK[dst]);
  };
  auto ENERGY = [&](int sv, int sh0, int sh1, const float* f1, const float* f2, float* eo) {
    k_energy<<<dim3(32), dim3(256), 0, stream>>>(PK[sv], PK[sh0], PK[sh1], f1, f2, b0, eo);
  };

  // gibbs step, fix_v=True.  F[IV] holds fv = v@W0.T + b1 (v constant in pos phase).
  auto gibbs_fixv = [&](u32 even, int t1, Key kh0, Key kh1) {
    GT(W1, SH0, b2, nullptr, F[IA]);                  // f_h1e = h0@W1.T + b2
    SAMP(F[IA], F[IA], ~0u, t1, kh1, SH1E);           // h1_e
    GN(W1, SH1E, nullptr, F[IV], F[IB]);              // f_h0e = fv + h1_e@W1
    GN(W1, SH1, nullptr, F[IV], F[IC]);               // f_h0o = fv + h1@W1
    SAMP(F[IC], F[IC], ~0u, t1, kh0, SH0O);           // h0_o
    GT(W1, SH0O, b2, nullptr, F[ID]);                 // f_h1o = h0_o@W1.T + b2
    SAMP(F[IB], F[IC], even, t1, kh0, SH0);           // h0 merge
    SAMP(F[IA], F[ID], even, t1, kh1, SH1);           // h1 merge
  };
  // gibbs step, fix_v=False.
  auto gibbs_free = [&](u32 even, int t1, Key kv, Key kh0, Key kh1) {
    GN(W0, SH0, b0, nullptr, F[IE]);                  // f_ve = h0@W0 + b0
    SAMP(F[IE], F[IE], ~0u, t1, kv, SVE);             // v_e
    GT(W1, SH0, b2, nullptr, F[IA]);                  // f_h1e
    SAMP(F[IA], F[IA], ~0u, t1, kh1, SH1E);           // h1_e
    GT(W0, SVE, b1, nullptr, F[IB]);                  // f_h0e = v_e@W0.T + b1
    GN(W1, SH1E, nullptr, F[IB], F[IB]);              //        + h1_e@W1
    GT(W0, SV, b1, nullptr, F[IC]);                   // f_h0o = v@W0.T + b1
    GN(W1, SH1, nullptr, F[IC], F[IC]);               //        + h1@W1
    SAMP(F[IC], F[IC], ~0u, t1, kh0, SH0O);           // h0_o
    GN(W0, SH0O, b0, nullptr, F[IF2]);                // f_vo = h0_o@W0 + b0
    GT(W1, SH0O, b2, nullptr, F[ID]);                 // f_h1o
    SAMP(F[IE], F[IF2], even, t1, kv, SV);            // v merge
    SAMP(F[IB], F[IC], even, t1, kh0, SH0);           // h0 merge
    SAMP(F[IA], F[ID], even, t1, kh1, SH1);           // h1 merge
  };

  // coupling: E_CUR must hold energy(cur); for fixv, F[IV] holds fv.
  auto coupling = [&](bool fixv, Key ck, float* erun) {
    Key top[2]; split_keys(ck, 2, top);               // k0, key
    Key cks[17]; cks[0] = top[0];
    { Key rest[16]; split_keys(top[1], 16, rest); for (int i = 0; i < 16; ++i) cks[i + 1] = rest[i]; }
    for (int it = 0; it < 17; ++it) {
      Key sub[4]; split_keys(cks[it], 4, sub);        // kv, kh0, kh1, ku
      UVec uv;
      for (int b = 0; b < NB; ++b) uv.u[b] = u01f(rbits(sub[3].a, sub[3].b, (u32)b, HALF_SMALL));
      if (!fixv) BERN(sub[0], SVP);
      BERN(sub[1], SH0P);
      BERN(sub[2], SH1P);
      const float* f1;
      if (fixv) f1 = F[IV];
      else { GT(W0, SVP, b1, nullptr, F[IP1]); f1 = F[IP1]; }
      GT(W1, SH0P, b2, nullptr, F[IP2]);
      ENERGY(fixv ? SV : SVP, SH0P, SH1P, f1, F[IP2], E_PROP);
      k_accept<<<dim3(32), dim3(64), 0, stream>>>(E_CUR, E_PROP, erun, CONV, ACC,
          fixv ? nullptr : PK[SVP], fixv ? nullptr : PK[SV],
          PK[SH0P], PK[SH0], PK[SH1P], PK[SH1], uv, it == 0 ? 1 : 0);
      k_merge_xf<<<dim3(768), dim3(256), 0, stream>>>(ACC, XF[SH0P], XF[SH0], XF[SH1P], XF[SH1],
          fixv ? nullptr : XF[SVP], fixv ? nullptr : XF[SV]);
      k_merge_pk<<<dim3(12), dim3(256), 0, stream>>>(ACC, PK[SH0P], PK[SH0], PK[SH1P], PK[SH1],
          fixv ? nullptr : PK[SVP], fixv ? nullptr : PK[SV]);
    }
  };

  // ================= positive phase =================
  k_pos_v<<<dim3(96), dim3(256), 0, stream>>>(vin, XF[SV], PK[SV]);
  BERN(ks[0], SH0);
  BERN(ks[1], SH1);
  GT(W0, SV, b1, nullptr, F[IV]);                     // fv = v@W0.T + b1 (constant in pos phase)
  u32 ev_ls_pos = mask32(ks[2]);
  for (int i = 0; i < 32; ++i) gibbs_fixv(ev_ls_pos, 0, KZ, KZ);
  u32 ev2_pos = mask32(ks[3]);
  Key g4[3]; split_keys(ks[4], 3, g4);                // kv(unused), kh0, kh1
  gibbs_fixv(ev2_pos, 1, g4[1], g4[2]);
  GT(W1, SH0, b2, nullptr, F[IC2]);                   // f2 for energy(cur)
  ENERGY(SV, SH0, SH1, F[IV], F[IC2], E_CUR);
  coupling(true, ks[5], E_POS);

  // ================= negative phase =================
  BERN(ks[6], SV);
  BERN(ks[7], SH0);
  BERN(ks[8], SH1);
  u32 ev_ls_neg = mask32(ks[9]);
  for (int i = 0; i < 32; ++i) gibbs_free(ev_ls_neg, 0, KZ, KZ, KZ);
  u32 ev2_neg = mask32(ks[10]);
  Key g11[3]; split_keys(ks[11], 3, g11);
  gibbs_free(ev2_neg, 1, g11[0], g11[1], g11[2]);
  GT(W0, SV, b1, nullptr, F[IB]);                     // f1 for energy(cur)
  GT(W1, SH0, b2, nullptr, F[IA]);                    // f2
  ENERGY(SV, SH0, SH1, F[IB], F[IA], E_CUR);
  coupling(false, ks[12], E_NEG);

  k_final<<<dim3(1), dim3(64), 0, stream>>>(E_POS, E_NEG, outp);
}